// Round 11
// baseline (1274.713 us; speedup 1.0000x reference)
//
#include <hip/hip_runtime.h>
#include <hip/hip_bf16.h>

#define D_DIM 1024
#define NTOK 267735
#define NEXT_ 267737   // + 2 cluster columns
#define HEADN 20000

typedef __attribute__((ext_vector_type(8))) short bf16x8;
typedef __attribute__((ext_vector_type(4))) float f32x4;

__device__ __forceinline__ int seg_of(int c){
  if (c < HEADN)  return 0;
  if (c < 20008)  return 1;
  if (c < 20016)  return 2;
  if (c < 200000) return 3;
  if (c < NTOK)   return 4;
  return 0; // cluster columns belong to head softmax
}

__device__ __forceinline__ unsigned pack2(float x, float y){
  __hip_bfloat16 a = __float2bfloat16(x);
  __hip_bfloat16 b = __float2bfloat16(y);
  unsigned short ua = *reinterpret_cast<unsigned short*>(&a);
  unsigned short ub = *reinterpret_cast<unsigned short*>(&b);
  return (unsigned)ua | ((unsigned)ub << 16);
}

#define BM 256
#define BN 128
#define BK 32
#define NTHREADS 512
#define KSTEPS (D_DIM/BK)   // 32
#define NCOLT 2092          // ceil(NEXT_/128)
#define NBLK 8384           // 8 XCD * 1048 (16 dead pad blocks)

#define APRIME_OFF 32768                      // byte offset of A' in ws
#define APRIME_BYTES (1024*1024*2)            // 2 MB bf16 fragment-ordered hidden

// Raw barrier WITHOUT the __syncthreads vmcnt(0) drain: LDS visibility needs
// only lgkmcnt(0); global prefetch loads stay in flight across the barrier
// (m201-verified pattern). The "memory" clobber pins compiler ordering.
#define BAR() do{ asm volatile("s_waitcnt lgkmcnt(0)" ::: "memory"); \
                  __builtin_amdgcn_s_barrier(); }while(0)

// LDS layout for B: [row][32] shorts (64B row). 16B chunk c of row r stored at
// chunk index c ^ ((r>>1)&3): writes conflict-free, b128 frag reads 2-way (free).
// Verified R2/R3/R5/R8: SQ_LDS_BANK_CONFLICT == 0.
__device__ __forceinline__ int swz_w(int r, int k4){   // short offset for 8B write
  int c = (k4 >> 1) ^ ((r >> 1) & 3);
  return r*32 + c*8 + (k4 & 1)*4;
}
__device__ __forceinline__ int swz_r(int row, int q){  // short offset for 16B read
  return row*32 + ((q ^ ((row >> 1) & 3)) << 3);
}

// Convert hidden (1024x1024 f32) -> A' bf16 in MFMA-fragment order:
// A'[rb(64)][kc(128)][r16(16)][e(8)]; wave frag load = 1024 contiguous bytes.
__global__ void prep_convert(const float* __restrict__ hidden,
                             unsigned short* __restrict__ Ap)
{
  int t = blockIdx.x * blockDim.x + threadIdx.x;   // 0..131071
  int r16 = t & 15, kc = (t >> 4) & 127, rb = t >> 11;
  const float4* src = reinterpret_cast<const float4*>(hidden + ((size_t)(rb*16 + r16) * D_DIM + kc*8));
  float4 x = src[0], y = src[1];
  uint4 o;
  o.x = pack2(x.x, x.y); o.y = pack2(x.z, x.w);
  o.z = pack2(y.x, y.y); o.w = pack2(y.z, y.w);
  reinterpret_cast<uint4*>(Ap)[t] = o;             // dst = t*16B: fully coalesced
}

// Per-(row, segment) sum of exp(logit + bias) into accg[row*8 + seg].
// R11: the counted-vmcnt pipeline. Raw s_barrier (no vmcnt drain) + A-frag
// register double-buffer (A(kt+1) issued at step kt, consumed one step later)
// + B issue-early/write-late into swizzled dbuf LDS. One barrier per step.
// Operating point: ~140 VGPR -> 8 waves/CU, 1 block (in-wave pipelining
// replaces the TLP lost; R7 tested this occupancy WITHOUT a working pipeline).
__global__ __launch_bounds__(NTHREADS, 1) void gemm_lse_adir(
    const unsigned short* __restrict__ Ap, const float* __restrict__ W,
    const float* __restrict__ bias,   const float* __restrict__ cw,
    const float* __restrict__ cb,     float* __restrict__ accg)
{
  const int b = blockIdx.x;
  const int k8 = b & 7;                // XCD slot
  const int sq_ = b >> 3;              // sequence within XCD
  const int xb = sq_ & 3;              // row-block 0..3 (sharers adjacent)
  const int yb = (sq_ >> 2) * 8 + k8;  // col-strip
  if (yb >= NCOLT) return;             // pad blocks

  __shared__ unsigned short lsB0[BN * 32];   // 8 KB
  __shared__ unsigned short lsB1[BN * 32];   // 8 KB

  const int tid = threadIdx.x;
  const int rowBase = xb * BM;
  const int colBase = yb * BN;

  // ---- B staging: 1024 float4s of the 128x32 f32 tile, 2/thread ----
  const float* bSrc0; const float* bSrc1; int bRow0, bRow1, bK40, bK41;
  {
    int idx = tid;            bRow0 = idx >> 3; bK40 = idx & 7;
    int c = colBase + bRow0;
    const float* base;
    if (c < NTOK)       base = W  + (size_t)c * D_DIM;
    else if (c < NEXT_) base = cw + (size_t)(c - NTOK) * D_DIM;
    else                base = W;
    bSrc0 = base + bK40*4;
  }
  {
    int idx = tid + NTHREADS; bRow1 = idx >> 3; bK41 = idx & 7;
    int c = colBase + bRow1;
    const float* base;
    if (c < NTOK)       base = W  + (size_t)c * D_DIM;
    else if (c < NEXT_) base = cw + (size_t)(c - NTOK) * D_DIM;
    else                base = W;
    bSrc1 = base + bK41*4;
  }

  const int lane = tid & 63;
  const int wv = tid >> 6;
  const int wm = wv >> 1;   // 0..3 : 64-row slab
  const int wn = wv & 1;    // 0..1 : 64-col slab
  const int q  = lane >> 4; // k-chunk
  const int r16 = lane & 15;

  const int wB0 = swz_w(bRow0, bK40), wB1 = swz_w(bRow1, bK41);
  const int rB0 = swz_r(wn*64 +  0 + r16, q), rB1 = swz_r(wn*64 + 16 + r16, q);
  const int rB2 = swz_r(wn*64 + 32 + r16, q), rB3 = swz_r(wn*64 + 48 + r16, q);

  // A' fragment pointers (ushort units): frag i at a_i + kt*512
  const unsigned short* a0 = Ap + (size_t)(xb*16 + wm*4 + 0)*16384 + q*128 + r16*8;
  const unsigned short* a1 = Ap + (size_t)(xb*16 + wm*4 + 1)*16384 + q*128 + r16*8;
  const unsigned short* a2 = Ap + (size_t)(xb*16 + wm*4 + 2)*16384 + q*128 + r16*8;
  const unsigned short* a3 = Ap + (size_t)(xb*16 + wm*4 + 3)*16384 + q*128 + r16*8;

  f32x4 acc[4][4];
#pragma unroll
  for (int i=0;i<4;++i)
#pragma unroll
    for (int j=0;j<4;++j) acc[i][j] = (f32x4){0.f,0.f,0.f,0.f};

  // two named A-fragment sets (register double-buffer; no arrays -> no scratch)
  bf16x8 xA0, xA1, xA2, xA3;   // set X
  bf16x8 yA0, yA1, yA2, yA3;   // set Y

#define LOAD_AX(kn) \
    xA0 = *reinterpret_cast<const bf16x8*>(a0 + (kn)*512); \
    xA1 = *reinterpret_cast<const bf16x8*>(a1 + (kn)*512); \
    xA2 = *reinterpret_cast<const bf16x8*>(a2 + (kn)*512); \
    xA3 = *reinterpret_cast<const bf16x8*>(a3 + (kn)*512);
#define LOAD_AY(kn) \
    yA0 = *reinterpret_cast<const bf16x8*>(a0 + (kn)*512); \
    yA1 = *reinterpret_cast<const bf16x8*>(a1 + (kn)*512); \
    yA2 = *reinterpret_cast<const bf16x8*>(a2 + (kn)*512); \
    yA3 = *reinterpret_cast<const bf16x8*>(a3 + (kn)*512);

#define MFMA16(A0,A1,A2,A3,L) { \
    bf16x8 bf0 = *reinterpret_cast<const bf16x8*>(&L[rB0]); \
    bf16x8 bf1 = *reinterpret_cast<const bf16x8*>(&L[rB1]); \
    bf16x8 bf2 = *reinterpret_cast<const bf16x8*>(&L[rB2]); \
    bf16x8 bf3 = *reinterpret_cast<const bf16x8*>(&L[rB3]); \
    acc[0][0] = __builtin_amdgcn_mfma_f32_16x16x32_bf16(A0, bf0, acc[0][0], 0,0,0); \
    acc[0][1] = __builtin_amdgcn_mfma_f32_16x16x32_bf16(A0, bf1, acc[0][1], 0,0,0); \
    acc[0][2] = __builtin_amdgcn_mfma_f32_16x16x32_bf16(A0, bf2, acc[0][2], 0,0,0); \
    acc[0][3] = __builtin_amdgcn_mfma_f32_16x16x32_bf16(A0, bf3, acc[0][3], 0,0,0); \
    acc[1][0] = __builtin_amdgcn_mfma_f32_16x16x32_bf16(A1, bf0, acc[1][0], 0,0,0); \
    acc[1][1] = __builtin_amdgcn_mfma_f32_16x16x32_bf16(A1, bf1, acc[1][1], 0,0,0); \
    acc[1][2] = __builtin_amdgcn_mfma_f32_16x16x32_bf16(A1, bf2, acc[1][2], 0,0,0); \
    acc[1][3] = __builtin_amdgcn_mfma_f32_16x16x32_bf16(A1, bf3, acc[1][3], 0,0,0); \
    acc[2][0] = __builtin_amdgcn_mfma_f32_16x16x32_bf16(A2, bf0, acc[2][0], 0,0,0); \
    acc[2][1] = __builtin_amdgcn_mfma_f32_16x16x32_bf16(A2, bf1, acc[2][1], 0,0,0); \
    acc[2][2] = __builtin_amdgcn_mfma_f32_16x16x32_bf16(A2, bf2, acc[2][2], 0,0,0); \
    acc[2][3] = __builtin_amdgcn_mfma_f32_16x16x32_bf16(A2, bf3, acc[2][3], 0,0,0); \
    acc[3][0] = __builtin_amdgcn_mfma_f32_16x16x32_bf16(A3, bf0, acc[3][0], 0,0,0); \
    acc[3][1] = __builtin_amdgcn_mfma_f32_16x16x32_bf16(A3, bf1, acc[3][1], 0,0,0); \
    acc[3][2] = __builtin_amdgcn_mfma_f32_16x16x32_bf16(A3, bf2, acc[3][2], 0,0,0); \
    acc[3][3] = __builtin_amdgcn_mfma_f32_16x16x32_bf16(A3, bf3, acc[3][3], 0,0,0); }

#define WRITE_B(L, v0, v1) { \
    unsigned* p; \
    p = reinterpret_cast<unsigned*>(&L[wB0]); p[0] = pack2(v0.x, v0.y); p[1] = pack2(v0.z, v0.w); \
    p = reinterpret_cast<unsigned*>(&L[wB1]); p[0] = pack2(v1.x, v1.y); p[1] = pack2(v1.z, v1.w); }

  // ---- prologue: A(0) -> setX ; B(0) -> lsB0 ----
  LOAD_AX(0);
  {
    float4 v0 = *reinterpret_cast<const float4*>(bSrc0);
    float4 v1 = *reinterpret_cast<const float4*>(bSrc1);
    WRITE_B(lsB0, v0, v1);
  }
  BAR();

  for (int kt2 = 0; kt2 < KSTEPS/2; ++kt2){
    // ---- even step kt=2k: compute from lsB0 with setX; prefetch kt+1 ----
    {
      const int kn = 2*kt2 + 1;     // always < KSTEPS
      float4 nb0 = *reinterpret_cast<const float4*>(bSrc0 + kn*BK);
      float4 nb1 = *reinterpret_cast<const float4*>(bSrc1 + kn*BK);
      LOAD_AY(kn);                  // in flight across this step's MFMAs + barrier
      MFMA16(xA0, xA1, xA2, xA3, lsB0);   // waits only setX (counted vmcnt)
      WRITE_B(lsB1, nb0, nb1);            // waits only nb (4 A-loads stay in flight)
      BAR();
    }
    // ---- odd step kt=2k+1: compute from lsB1 with setY; prefetch kt+2 ----
    {
      const int kn = 2*kt2 + 2;
      if (kn < KSTEPS){
        float4 nb0 = *reinterpret_cast<const float4*>(bSrc0 + kn*BK);
        float4 nb1 = *reinterpret_cast<const float4*>(bSrc1 + kn*BK);
        LOAD_AX(kn);
        MFMA16(yA0, yA1, yA2, yA3, lsB1);
        WRITE_B(lsB0, nb0, nb1);
        BAR();
      } else {
        MFMA16(yA0, yA1, yA2, yA3, lsB1);
      }
    }
  }

  // ---- fused epilogue: exp + segmented reduce + atomic ----
  int sq[4]; float bq[4];
#pragma unroll
  for (int f=0; f<4; ++f){
    int c = colBase + wn*64 + f*16 + r16;
    if (c < NTOK)       { sq[f] = seg_of(c); bq[f] = bias[c]; }
    else if (c < NEXT_) { sq[f] = 0;         bq[f] = cb[c - NTOK]; }
    else                { sq[f] = -1;        bq[f] = 0.f; }
  }
  int sfirst = seg_of(colBase);
  int clast  = colBase + BN - 1; if (clast > NEXT_-1) clast = NEXT_-1;
  int slast  = seg_of(clast);
  int smin = sfirst, smax = slast;
  if (slast < sfirst){ smin = 0; smax = 4; }   // wrap tile at N_TOKEN boundary

#pragma unroll
  for (int i=0;i<4;++i){
#pragma unroll
    for (int r=0;r<4;++r){
      float e[4];
#pragma unroll
      for (int f=0;f<4;++f) e[f] = __expf(acc[i][f][r] + bq[f]);
      int rowg = rowBase + wm*64 + i*16 + (lane>>4)*4 + r;   // C/D: row=(l>>4)*4+reg
      for (int s2 = smin; s2 <= smax; ++s2){
        float p = 0.f;
#pragma unroll
        for (int f=0;f<4;++f) p += (sq[f]==s2) ? e[f] : 0.f;
#pragma unroll
        for (int off=1; off<16; off<<=1) p += __shfl_xor(p, off, 16);
        if ((lane & 15) == 0 && p != 0.f) atomicAdd(&accg[rowg*8 + s2], p);
      }
    }
  }
}

// One wave per row: target logit + routing logit + final nll.
__global__ __launch_bounds__(256) void finalize_kernel(
    const float* __restrict__ hidden, const int* __restrict__ target,
    const float* __restrict__ W,      const float* __restrict__ bias,
    const float* __restrict__ cw,     const float* __restrict__ cb,
    const float* __restrict__ accg,   float* __restrict__ out)
{
  const int row  = blockIdx.x * 4 + (threadIdx.x >> 6);
  const int lane = threadIdx.x & 63;
  const int t = target[row];

  const float4* h4 = reinterpret_cast<const float4*>(hidden + (size_t)row * D_DIM);
  const float4* w1 = reinterpret_cast<const float4*>(W + (size_t)t * D_DIM);
  int s = 0; const float* jraw = W; float jb = 0.f;
  if (t >= HEADN){
    if      (t < 20008)  { s=1; jraw = W;          jb = bias[0]; }  // j = 0
    else if (t < 20016)  { s=2; jraw = W + D_DIM;  jb = bias[1]; }  // j = 1
    else if (t < 200000) { s=3; jraw = cw + D_DIM; jb = cb[1];   }  // j = 20001 -> cluster 1
    else                 { s=4; jraw = cw;         jb = cb[0];   }  // j = 20000 -> cluster 0
  }
  const float4* w2 = reinterpret_cast<const float4*>(jraw);

  float p1 = 0.f, p2 = 0.f;
#pragma unroll
  for (int j=0;j<4;++j){
    float4 hv = h4[lane + 64*j];
    float4 av = w1[lane + 64*j];
    float4 bv = w2[lane + 64*j];
    p1 += hv.x*av.x + hv.y*av.y + hv.z*av.z + hv.w*av.w;
    p2 += hv.x*bv.x + hv.y*bv.y + hv.z*bv.z + hv.w*bv.w;
  }
#pragma unroll
  for (int off=32; off; off>>=1){
    p1 += __shfl_xor(p1, off, 64);
    p2 += __shfl_xor(p2, off, 64);
  }

  if (lane == 0){
    float lseH = __logf(accg[row*8 + 0]);
    float nll;
    if (t < HEADN){
      nll = -(p1 + bias[t] - lseH);
    } else {
      float lseS = __logf(accg[row*8 + s]);
      nll = -((p2 + jb - lseH) + (p1 + bias[t] - lseS));
    }
    out[row] = nll;
  }
}

extern "C" void kernel_launch(void* const* d_in, const int* in_sizes, int n_in,
                              void* d_out, int out_size, void* d_ws, size_t ws_size,
                              hipStream_t stream)
{
  const float* hidden = (const float*)d_in[0];
  const int*   target = (const int*)  d_in[1];
  const float* W      = (const float*)d_in[2];
  const float* bias   = (const float*)d_in[3];
  const float* cw     = (const float*)d_in[4];
  const float* cb     = (const float*)d_in[5];
  float* out  = (float*)d_out;
  float* accg = (float*)d_ws;          // [1024][8] fp32 sum-of-exp accumulators
  unsigned short* Ap = (unsigned short*)((char*)d_ws + APRIME_OFF);

  hipMemsetAsync(accg, 0, 1024*8*sizeof(float), stream);

  prep_convert<<<512, 256, 0, stream>>>(hidden, Ap);
  gemm_lse_adir<<<NBLK, NTHREADS, 0, stream>>>(Ap, W, bias, cw, cb, accg);
  finalize_kernel<<<256, 256, 0, stream>>>(hidden, target, W, bias, cw, cb, accg, out);
}

// Round 12
// 887.451 us; speedup vs baseline: 1.4364x; 1.4364x over previous
//
#include <hip/hip_runtime.h>
#include <hip/hip_bf16.h>

#define D_DIM 1024
#define NTOK 267735
#define NEXT_ 267737   // + 2 cluster columns
#define HEADN 20000

typedef __attribute__((ext_vector_type(8))) short bf16x8;
typedef __attribute__((ext_vector_type(4))) float f32x4;
typedef __attribute__((ext_vector_type(4))) unsigned uint4v;

__device__ __forceinline__ int seg_of(int c){
  if (c < HEADN)  return 0;
  if (c < 20008)  return 1;
  if (c < 20016)  return 2;
  if (c < 200000) return 3;
  if (c < NTOK)   return 4;
  return 0; // cluster columns belong to head softmax
}

__device__ __forceinline__ unsigned pack2(float x, float y){
  __hip_bfloat16 a = __float2bfloat16(x);
  __hip_bfloat16 b = __float2bfloat16(y);
  unsigned short ua = *reinterpret_cast<unsigned short*>(&a);
  unsigned short ub = *reinterpret_cast<unsigned short*>(&b);
  return (unsigned)ua | ((unsigned)ub << 16);
}

#define BM 256
#define BN 128
#define BK 32
#define NTHREADS 512
#define KSTEPS (D_DIM/BK)   // 32
#define NCOLT 2092          // ceil(NEXT_/128)
#define NBLK 8384           // 8 XCD * 1048 (16 dead pad blocks)

#define APRIME_OFF 32768                      // byte offset of A' in ws
#define APRIME_BYTES (1024*1024*2)            // 2 MB bf16 fragment-ordered hidden

// direct global->LDS (16B/lane). Dest is wave-uniform base + lane*16 (m104);
// source address is per-lane.
__device__ __forceinline__ void stage16(const float* g, unsigned short* l){
  __builtin_amdgcn_global_load_lds(
      (const __attribute__((address_space(1))) void*)g,
      (__attribute__((address_space(3))) void*)l, 16, 0, 0);
}

// Convert hidden (1024x1024 f32) -> A' bf16 in MFMA-fragment order:
// A'[rb(64)][kc(128)][r16(16)][e(8)]; wave frag load = 1024 contiguous bytes.
__global__ void prep_convert(const float* __restrict__ hidden,
                             unsigned short* __restrict__ Ap)
{
  int t = blockIdx.x * blockDim.x + threadIdx.x;   // 0..131071
  int r16 = t & 15, kc = (t >> 4) & 127, rb = t >> 11;
  const float4* src = reinterpret_cast<const float4*>(hidden + ((size_t)(rb*16 + r16) * D_DIM + kc*8));
  float4 x = src[0], y = src[1];
  uint4 o;
  o.x = pack2(x.x, x.y); o.y = pack2(x.z, x.w);
  o.z = pack2(y.x, y.y); o.w = pack2(y.z, y.w);
  reinterpret_cast<uint4*>(Ap)[t] = o;             // dst = t*16B: fully coalesced
}

// Per-(row, segment) sum of exp(logit + bias) into accg[row*8 + seg].
// R12: B staged fp32 via global_load_lds (no reg round-trip, no producer cvt,
// no producer VALU). LDS dest linear (HW constraint) -> bank swizzle applied
// on the SOURCE: thread f stages k4 = (f&7) ^ (row&7) (permutation within the
// row's 128B segment -> source stays coalesced); reader applies the same XOR
// (both-sides involution). Consumer converts fp32->bf16 at fragment read.
// A direct-from-global in fragment order (R8). One __syncthreads per step
// (its vmcnt(0) drain publishes the stage; stage had the MFMA phase to fly —
// m97 structure). A loads issued BEFORE the stage so MFMA's counted vmcnt
// leaves the stage in flight. Reg budget: ~60 arch + 64 acc -> 2 blocks/CU.
__global__ __launch_bounds__(NTHREADS, 1) void gemm_lse_adir(
    const unsigned short* __restrict__ Ap, const float* __restrict__ W,
    const float* __restrict__ bias,   const float* __restrict__ cw,
    const float* __restrict__ cb,     float* __restrict__ accg)
{
  const int b = blockIdx.x;
  const int k8 = b & 7;                // XCD slot
  const int sq_ = b >> 3;              // sequence within XCD
  const int xb = sq_ & 3;              // row-block 0..3 (sharers adjacent)
  const int yb = (sq_ >> 2) * 8 + k8;  // col-strip
  if (yb >= NCOLT) return;             // pad blocks

  // B double buffer: fp32 tile 128 rows x 32 k = 16 KB each.
  // layout: [row][k4slot] float4s, linear in f = row*8 + k4slot.
  __shared__ unsigned short lsB0[BN * 64];   // 16 KB
  __shared__ unsigned short lsB1[BN * 64];   // 16 KB

  const int tid = threadIdx.x;
  const int rowBase = xb * BM;
  const int colBase = yb * BN;

  const int lane = tid & 63;
  const int wv = tid >> 6;
  const int wm = wv >> 1;   // 0..3 : 64-row slab
  const int wn = wv & 1;    // 0..1 : 64-col slab
  const int q  = lane >> 4; // k-chunk
  const int r16 = lane & 15;

  // ---- B stage source pointers (2 per thread; f = i*512 + tid) ----
  const float* sp0; const float* sp1;
  {
    int f = tid;        int row = f >> 3; int kc = (f & 7) ^ (row & 7);
    int c = colBase + row;
    const float* base = (c < NTOK)  ? (W  + (size_t)c * D_DIM)
                      : (c < NEXT_) ? (cw + (size_t)(c - NTOK) * D_DIM) : W;
    sp0 = base + kc*4;
  }
  {
    int f = 512 + tid;  int row = f >> 3; int kc = (f & 7) ^ (row & 7);
    int c = colBase + row;
    const float* base = (c < NTOK)  ? (W  + (size_t)c * D_DIM)
                      : (c < NEXT_) ? (cw + (size_t)(c - NTOK) * D_DIM) : W;
    sp1 = base + kc*4;
  }
  // wave-uniform LDS dest bases (ushort units; lane*16B added by HW)
  const int dst0 = wv*512;          // i=0 region: f in [wv*64, wv*64+64)
  const int dst1 = 4096 + wv*512;   // i=1 region

#define STAGE(Lbuf, kn) do{ \
    stage16(sp0 + (kn)*BK, &Lbuf[dst0]); \
    stage16(sp1 + (kn)*BK, &Lbuf[dst1]); }while(0)

  // ---- consumer B-fragment offsets (ushort units; row stride 64) ----
  int loO[4], hiO[4];
#pragma unroll
  for (int j=0;j<4;++j){
    int row = wn*64 + j*16 + r16;
    loO[j] = row*64 + (((2*q  ) ^ (row & 7)) << 3);
    hiO[j] = row*64 + (((2*q+1) ^ (row & 7)) << 3);
  }

  // A' fragment pointers (ushort units): frag i at a_i + kt*512
  const unsigned short* a0 = Ap + (size_t)(xb*16 + wm*4 + 0)*16384 + q*128 + r16*8;
  const unsigned short* a1 = Ap + (size_t)(xb*16 + wm*4 + 1)*16384 + q*128 + r16*8;
  const unsigned short* a2 = Ap + (size_t)(xb*16 + wm*4 + 2)*16384 + q*128 + r16*8;
  const unsigned short* a3 = Ap + (size_t)(xb*16 + wm*4 + 3)*16384 + q*128 + r16*8;

  f32x4 acc[4][4];
#pragma unroll
  for (int i=0;i<4;++i)
#pragma unroll
    for (int j=0;j<4;++j) acc[i][j] = (f32x4){0.f,0.f,0.f,0.f};

#define BFRAG(Lr, j, out) { \
    float4 lo = *reinterpret_cast<const float4*>(&Lr[loO[j]]); \
    float4 hi = *reinterpret_cast<const float4*>(&Lr[hiO[j]]); \
    uint4v uu; \
    uu.x = pack2(lo.x, lo.y); uu.y = pack2(lo.z, lo.w); \
    uu.z = pack2(hi.x, hi.y); uu.w = pack2(hi.z, hi.w); \
    out = __builtin_bit_cast(bf16x8, uu); }

  // ---- prologue: stage B(0) into buf0 ----
  STAGE(lsB0, 0);
  __syncthreads();   // vmcnt(0)+lgkmcnt(0) drain publishes the stage

  for (int kt = 0; kt < KSTEPS; ++kt){
    unsigned short* Lr = (kt & 1) ? lsB1 : lsB0;
    unsigned short* Lw = (kt & 1) ? lsB0 : lsB1;

    // A frags first (so MFMA's counted vmcnt wait leaves the stage in flight)
    bf16x8 af0 = *reinterpret_cast<const bf16x8*>(a0 + kt*512);
    bf16x8 af1 = *reinterpret_cast<const bf16x8*>(a1 + kt*512);
    bf16x8 af2 = *reinterpret_cast<const bf16x8*>(a2 + kt*512);
    bf16x8 af3 = *reinterpret_cast<const bf16x8*>(a3 + kt*512);

    if (kt + 1 < KSTEPS) STAGE(Lw, kt+1);   // flies under this step's MFMAs

    bf16x8 b0, b1, b2, b3;
    BFRAG(Lr, 0, b0); BFRAG(Lr, 1, b1); BFRAG(Lr, 2, b2); BFRAG(Lr, 3, b3);

    acc[0][0] = __builtin_amdgcn_mfma_f32_16x16x32_bf16(af0, b0, acc[0][0], 0,0,0);
    acc[0][1] = __builtin_amdgcn_mfma_f32_16x16x32_bf16(af0, b1, acc[0][1], 0,0,0);
    acc[0][2] = __builtin_amdgcn_mfma_f32_16x16x32_bf16(af0, b2, acc[0][2], 0,0,0);
    acc[0][3] = __builtin_amdgcn_mfma_f32_16x16x32_bf16(af0, b3, acc[0][3], 0,0,0);
    acc[1][0] = __builtin_amdgcn_mfma_f32_16x16x32_bf16(af1, b0, acc[1][0], 0,0,0);
    acc[1][1] = __builtin_amdgcn_mfma_f32_16x16x32_bf16(af1, b1, acc[1][1], 0,0,0);
    acc[1][2] = __builtin_amdgcn_mfma_f32_16x16x32_bf16(af1, b2, acc[1][2], 0,0,0);
    acc[1][3] = __builtin_amdgcn_mfma_f32_16x16x32_bf16(af1, b3, acc[1][3], 0,0,0);
    acc[2][0] = __builtin_amdgcn_mfma_f32_16x16x32_bf16(af2, b0, acc[2][0], 0,0,0);
    acc[2][1] = __builtin_amdgcn_mfma_f32_16x16x32_bf16(af2, b1, acc[2][1], 0,0,0);
    acc[2][2] = __builtin_amdgcn_mfma_f32_16x16x32_bf16(af2, b2, acc[2][2], 0,0,0);
    acc[2][3] = __builtin_amdgcn_mfma_f32_16x16x32_bf16(af2, b3, acc[2][3], 0,0,0);
    acc[3][0] = __builtin_amdgcn_mfma_f32_16x16x32_bf16(af3, b0, acc[3][0], 0,0,0);
    acc[3][1] = __builtin_amdgcn_mfma_f32_16x16x32_bf16(af3, b1, acc[3][1], 0,0,0);
    acc[3][2] = __builtin_amdgcn_mfma_f32_16x16x32_bf16(af3, b2, acc[3][2], 0,0,0);
    acc[3][3] = __builtin_amdgcn_mfma_f32_16x16x32_bf16(af3, b3, acc[3][3], 0,0,0);

    __syncthreads();   // drains vmcnt(0): stage(kt+1) complete & visible
  }

  // ---- fused epilogue: exp + segmented reduce + atomic ----
  int sq[4]; float bq[4];
#pragma unroll
  for (int f=0; f<4; ++f){
    int c = colBase + wn*64 + f*16 + r16;
    if (c < NTOK)       { sq[f] = seg_of(c); bq[f] = bias[c]; }
    else if (c < NEXT_) { sq[f] = 0;         bq[f] = cb[c - NTOK]; }
    else                { sq[f] = -1;        bq[f] = 0.f; }
  }
  int sfirst = seg_of(colBase);
  int clast  = colBase + BN - 1; if (clast > NEXT_-1) clast = NEXT_-1;
  int slast  = seg_of(clast);
  int smin = sfirst, smax = slast;
  if (slast < sfirst){ smin = 0; smax = 4; }   // wrap tile at N_TOKEN boundary

#pragma unroll
  for (int i=0;i<4;++i){
#pragma unroll
    for (int r=0;r<4;++r){
      float e[4];
#pragma unroll
      for (int f=0;f<4;++f) e[f] = __expf(acc[i][f][r] + bq[f]);
      int rowg = rowBase + wm*64 + i*16 + (lane>>4)*4 + r;   // C/D: row=(l>>4)*4+reg
      for (int s2 = smin; s2 <= smax; ++s2){
        float p = 0.f;
#pragma unroll
        for (int f=0;f<4;++f) p += (sq[f]==s2) ? e[f] : 0.f;
#pragma unroll
        for (int off=1; off<16; off<<=1) p += __shfl_xor(p, off, 16);
        if ((lane & 15) == 0 && p != 0.f) atomicAdd(&accg[rowg*8 + s2], p);
      }
    }
  }
}

// One wave per row: target logit + routing logit + final nll.
__global__ __launch_bounds__(256) void finalize_kernel(
    const float* __restrict__ hidden, const int* __restrict__ target,
    const float* __restrict__ W,      const float* __restrict__ bias,
    const float* __restrict__ cw,     const float* __restrict__ cb,
    const float* __restrict__ accg,   float* __restrict__ out)
{
  const int row  = blockIdx.x * 4 + (threadIdx.x >> 6);
  const int lane = threadIdx.x & 63;
  const int t = target[row];

  const float4* h4 = reinterpret_cast<const float4*>(hidden + (size_t)row * D_DIM);
  const float4* w1 = reinterpret_cast<const float4*>(W + (size_t)t * D_DIM);
  int s = 0; const float* jraw = W; float jb = 0.f;
  if (t >= HEADN){
    if      (t < 20008)  { s=1; jraw = W;          jb = bias[0]; }  // j = 0
    else if (t < 20016)  { s=2; jraw = W + D_DIM;  jb = bias[1]; }  // j = 1
    else if (t < 200000) { s=3; jraw = cw + D_DIM; jb = cb[1];   }  // j = 20001 -> cluster 1
    else                 { s=4; jraw = cw;         jb = cb[0];   }  // j = 20000 -> cluster 0
  }
  const float4* w2 = reinterpret_cast<const float4*>(jraw);

  float p1 = 0.f, p2 = 0.f;
#pragma unroll
  for (int j=0;j<4;++j){
    float4 hv = h4[lane + 64*j];
    float4 av = w1[lane + 64*j];
    float4 bv = w2[lane + 64*j];
    p1 += hv.x*av.x + hv.y*av.y + hv.z*av.z + hv.w*av.w;
    p2 += hv.x*bv.x + hv.y*bv.y + hv.z*bv.z + hv.w*bv.w;
  }
#pragma unroll
  for (int off=32; off; off>>=1){
    p1 += __shfl_xor(p1, off, 64);
    p2 += __shfl_xor(p2, off, 64);
  }

  if (lane == 0){
    float lseH = __logf(accg[row*8 + 0]);
    float nll;
    if (t < HEADN){
      nll = -(p1 + bias[t] - lseH);
    } else {
      float lseS = __logf(accg[row*8 + s]);
      nll = -((p2 + jb - lseH) + (p1 + bias[t] - lseS));
    }
    out[row] = nll;
  }
}

extern "C" void kernel_launch(void* const* d_in, const int* in_sizes, int n_in,
                              void* d_out, int out_size, void* d_ws, size_t ws_size,
                              hipStream_t stream)
{
  const float* hidden = (const float*)d_in[0];
  const int*   target = (const int*)  d_in[1];
  const float* W      = (const float*)d_in[2];
  const float* bias   = (const float*)d_in[3];
  const float* cw     = (const float*)d_in[4];
  const float* cb     = (const float*)d_in[5];
  float* out  = (float*)d_out;
  float* accg = (float*)d_ws;          // [1024][8] fp32 sum-of-exp accumulators
  unsigned short* Ap = (unsigned short*)((char*)d_ws + APRIME_OFF);

  hipMemsetAsync(accg, 0, 1024*8*sizeof(float), stream);

  prep_convert<<<512, 256, 0, stream>>>(hidden, Ap);
  gemm_lse_adir<<<NBLK, NTHREADS, 0, stream>>>(Ap, W, bias, cw, cb, accg);
  finalize_kernel<<<256, 256, 0, stream>>>(hidden, target, W, bias, cw, cb, accg, out);
}

// Round 13
// 830.740 us; speedup vs baseline: 1.5344x; 1.0683x over previous
//
#include <hip/hip_runtime.h>
#include <hip/hip_bf16.h>

#define D_DIM 1024
#define NTOK 267735
#define NEXT_ 267737   // + 2 cluster columns
#define HEADN 20000

typedef __attribute__((ext_vector_type(8))) short bf16x8;
typedef __attribute__((ext_vector_type(4))) float f32x4;
typedef __attribute__((ext_vector_type(4))) unsigned uint4v;

__device__ __forceinline__ int seg_of(int c){
  if (c < HEADN)  return 0;
  if (c < 20008)  return 1;
  if (c < 20016)  return 2;
  if (c < 200000) return 3;
  if (c < NTOK)   return 4;
  return 0; // cluster columns belong to head softmax
}

__device__ __forceinline__ unsigned pack2(float x, float y){
  __hip_bfloat16 a = __float2bfloat16(x);
  __hip_bfloat16 b = __float2bfloat16(y);
  unsigned short ua = *reinterpret_cast<unsigned short*>(&a);
  unsigned short ub = *reinterpret_cast<unsigned short*>(&b);
  return (unsigned)ua | ((unsigned)ub << 16);
}

#define BM 256
#define BN 128
#define BK 32
#define NTHREADS 512
#define KSTEPS (D_DIM/BK)   // 32
#define NCOLT 2092          // ceil(NEXT_/128)
#define NBLK 8384           // 8 XCD * 1048 (16 dead pad blocks)

#define APRIME_OFF 32768                      // byte offset of A' in ws
#define APRIME_BYTES (1024*1024*2)            // 2 MB bf16 fragment-ordered hidden

// direct global->LDS (16B/lane). Dest is wave-uniform base + lane*16 (m104);
// source address is per-lane.
__device__ __forceinline__ void stage16(const float* g, unsigned short* l){
  __builtin_amdgcn_global_load_lds(
      (const __attribute__((address_space(1))) void*)g,
      (__attribute__((address_space(3))) void*)l, 16, 0, 0);
}

// packed fp32x2 -> bf16x2 (single VALU op; pack2's scalar path may lower to
// the multi-op RTNE integer sequence). Low half = x.
#define CVTPK(d, x, y) asm("v_cvt_pk_bf16_f32 %0, %1, %2" : "=v"(d) : "v"(x), "v"(y))

// Convert hidden (1024x1024 f32) -> A' bf16 in MFMA-fragment order:
// A'[rb(64)][kc(128)][r16(16)][e(8)]; wave frag load = 1024 contiguous bytes.
__global__ void prep_convert(const float* __restrict__ hidden,
                             unsigned short* __restrict__ Ap)
{
  int t = blockIdx.x * blockDim.x + threadIdx.x;   // 0..131071
  int r16 = t & 15, kc = (t >> 4) & 127, rb = t >> 11;
  const float4* src = reinterpret_cast<const float4*>(hidden + ((size_t)(rb*16 + r16) * D_DIM + kc*8));
  float4 x = src[0], y = src[1];
  uint4 o;
  o.x = pack2(x.x, x.y); o.y = pack2(x.z, x.w);
  o.z = pack2(y.x, y.y); o.w = pack2(y.z, y.w);
  reinterpret_cast<uint4*>(Ap)[t] = o;             // dst = t*16B: fully coalesced
}

// Per-(row, segment) sum of exp(logit + bias) into accg[row*8 + seg].
// R13 = R12 structure with two measured fixes:
//  (a) B LDS layout [h(2)][row(128)][16 floats] — 64 B rows restore the
//      R5-proven bank pattern: slot = (row&1)*4 + (c ^ ((row>>1)&3)); the
//      source-side permutation (per-lane global addr) keeps the DMA dest
//      linear; the read applies the same XOR (both-sides involution).
//  (b) consumer cvt via v_cvt_pk_bf16_f32 (4 VALU ops per fragment).
// A direct-from-global in fragment order (R8). One __syncthreads per step;
// A loads issued BEFORE the stage so MFMA's counted vmcnt leaves the stage
// in flight; the stage has the MFMA phase to complete.
__global__ __launch_bounds__(NTHREADS, 1) void gemm_lse_adir(
    const unsigned short* __restrict__ Ap, const float* __restrict__ W,
    const float* __restrict__ bias,   const float* __restrict__ cw,
    const float* __restrict__ cb,     float* __restrict__ accg)
{
  const int b = blockIdx.x;
  const int k8 = b & 7;                // XCD slot
  const int sq_ = b >> 3;              // sequence within XCD
  const int xb = sq_ & 3;              // row-block 0..3 (sharers adjacent)
  const int yb = (sq_ >> 2) * 8 + k8;  // col-strip
  if (yb >= NCOLT) return;             // pad blocks

  // B double buffer: fp32 tile as [h][row][16 floats] = 16 KB each.
  __shared__ unsigned short lsB0[BN * 64];   // 16 KB
  __shared__ unsigned short lsB1[BN * 64];   // 16 KB

  const int tid = threadIdx.x;
  const int rowBase = xb * BM;
  const int colBase = yb * BN;

  const int lane = tid & 63;
  const int wv = tid >> 6;
  const int wm = wv >> 1;   // 0..3 : 64-row slab
  const int wn = wv & 1;    // 0..1 : 64-col slab
  const int q  = lane >> 4; // k-chunk
  const int r16 = lane & 15;

  // ---- B stage source pointer (one per thread; s1 at +16 floats) ----
  // stage s (s=0: h=0/k 0-15, s=1: h=1/k 16-31) of wave wv covers rows
  // wv*16..wv*16+16. lane -> (row_local = lane>>2, dest chunk = lane&3);
  // source chunk c = (lane&3) ^ ((row>>1)&3)  [involution with the read].
  const float* sp;
  {
    int srow = wv*16 + (lane >> 2);
    int c    = (lane & 3) ^ ((srow >> 1) & 3);
    int col  = colBase + srow;
    const float* base = (col < NTOK)  ? (W  + (size_t)col * D_DIM)
                      : (col < NEXT_) ? (cw + (size_t)(col - NTOK) * D_DIM) : W;
    sp = base + c*4;
  }
  // wave-uniform LDS dest bases (ushort units; lane*16B added by HW)
  const int dstH0 = wv*512;            // h=0 region of this wave's 16 rows
  const int dstH1 = 4096 + wv*512;     // h=1 region

#define STAGE(Lbuf, kn) do{ \
    stage16(sp + (kn)*BK,      &Lbuf[dstH0]); \
    stage16(sp + (kn)*BK + 16, &Lbuf[dstH1]); }while(0)

  // ---- consumer B-fragment offsets (ushort units) ----
  // frag j, this lane: row = wn*64+j*16+r16, needs k4 = 2q (lo) and 2q+1 (hi);
  // h = q>>1; stored chunk = (k4&3) ^ ((row>>1)&3).
  int loO[4], hiO[4];
#pragma unroll
  for (int j=0;j<4;++j){
    int row = wn*64 + j*16 + r16;
    int swz = (row >> 1) & 3;
    int h   = q >> 1;
    loO[j] = h*4096 + row*32 + (((2*q  ) & 3) ^ swz)*8;
    hiO[j] = h*4096 + row*32 + (((2*q+1) & 3) ^ swz)*8;
  }

  // A' fragment pointers (ushort units): frag i at a_i + kt*512
  const unsigned short* a0 = Ap + (size_t)(xb*16 + wm*4 + 0)*16384 + q*128 + r16*8;
  const unsigned short* a1 = Ap + (size_t)(xb*16 + wm*4 + 1)*16384 + q*128 + r16*8;
  const unsigned short* a2 = Ap + (size_t)(xb*16 + wm*4 + 2)*16384 + q*128 + r16*8;
  const unsigned short* a3 = Ap + (size_t)(xb*16 + wm*4 + 3)*16384 + q*128 + r16*8;

  f32x4 acc[4][4];
#pragma unroll
  for (int i=0;i<4;++i)
#pragma unroll
    for (int j=0;j<4;++j) acc[i][j] = (f32x4){0.f,0.f,0.f,0.f};

#define BFRAG(Lr, j, out) { \
    float4 lo = *reinterpret_cast<const float4*>(&Lr[loO[j]]); \
    float4 hi = *reinterpret_cast<const float4*>(&Lr[hiO[j]]); \
    unsigned u0,u1,u2,u3; \
    CVTPK(u0, lo.x, lo.y); CVTPK(u1, lo.z, lo.w); \
    CVTPK(u2, hi.x, hi.y); CVTPK(u3, hi.z, hi.w); \
    uint4v uu; uu.x=u0; uu.y=u1; uu.z=u2; uu.w=u3; \
    out = __builtin_bit_cast(bf16x8, uu); }

  // ---- prologue: stage B(0) into buf0 ----
  STAGE(lsB0, 0);
  __syncthreads();   // vmcnt(0)+lgkmcnt(0) drain publishes the stage

  for (int kt = 0; kt < KSTEPS; ++kt){
    unsigned short* Lr = (kt & 1) ? lsB1 : lsB0;
    unsigned short* Lw = (kt & 1) ? lsB0 : lsB1;

    // A frags first (so MFMA's counted vmcnt wait leaves the stage in flight)
    bf16x8 af0 = *reinterpret_cast<const bf16x8*>(a0 + kt*512);
    bf16x8 af1 = *reinterpret_cast<const bf16x8*>(a1 + kt*512);
    bf16x8 af2 = *reinterpret_cast<const bf16x8*>(a2 + kt*512);
    bf16x8 af3 = *reinterpret_cast<const bf16x8*>(a3 + kt*512);

    if (kt + 1 < KSTEPS) STAGE(Lw, kt+1);   // flies under this step's MFMAs

    bf16x8 b0, b1, b2, b3;
    BFRAG(Lr, 0, b0); BFRAG(Lr, 1, b1); BFRAG(Lr, 2, b2); BFRAG(Lr, 3, b3);

    acc[0][0] = __builtin_amdgcn_mfma_f32_16x16x32_bf16(af0, b0, acc[0][0], 0,0,0);
    acc[0][1] = __builtin_amdgcn_mfma_f32_16x16x32_bf16(af0, b1, acc[0][1], 0,0,0);
    acc[0][2] = __builtin_amdgcn_mfma_f32_16x16x32_bf16(af0, b2, acc[0][2], 0,0,0);
    acc[0][3] = __builtin_amdgcn_mfma_f32_16x16x32_bf16(af0, b3, acc[0][3], 0,0,0);
    acc[1][0] = __builtin_amdgcn_mfma_f32_16x16x32_bf16(af1, b0, acc[1][0], 0,0,0);
    acc[1][1] = __builtin_amdgcn_mfma_f32_16x16x32_bf16(af1, b1, acc[1][1], 0,0,0);
    acc[1][2] = __builtin_amdgcn_mfma_f32_16x16x32_bf16(af1, b2, acc[1][2], 0,0,0);
    acc[1][3] = __builtin_amdgcn_mfma_f32_16x16x32_bf16(af1, b3, acc[1][3], 0,0,0);
    acc[2][0] = __builtin_amdgcn_mfma_f32_16x16x32_bf16(af2, b0, acc[2][0], 0,0,0);
    acc[2][1] = __builtin_amdgcn_mfma_f32_16x16x32_bf16(af2, b1, acc[2][1], 0,0,0);
    acc[2][2] = __builtin_amdgcn_mfma_f32_16x16x32_bf16(af2, b2, acc[2][2], 0,0,0);
    acc[2][3] = __builtin_amdgcn_mfma_f32_16x16x32_bf16(af2, b3, acc[2][3], 0,0,0);
    acc[3][0] = __builtin_amdgcn_mfma_f32_16x16x32_bf16(af3, b0, acc[3][0], 0,0,0);
    acc[3][1] = __builtin_amdgcn_mfma_f32_16x16x32_bf16(af3, b1, acc[3][1], 0,0,0);
    acc[3][2] = __builtin_amdgcn_mfma_f32_16x16x32_bf16(af3, b2, acc[3][2], 0,0,0);
    acc[3][3] = __builtin_amdgcn_mfma_f32_16x16x32_bf16(af3, b3, acc[3][3], 0,0,0);

    __syncthreads();   // drains vmcnt(0): stage(kt+1) complete & visible
  }

  // ---- fused epilogue: exp + segmented reduce + atomic ----
  int sq[4]; float bq[4];
#pragma unroll
  for (int f=0; f<4; ++f){
    int c = colBase + wn*64 + f*16 + r16;
    if (c < NTOK)       { sq[f] = seg_of(c); bq[f] = bias[c]; }
    else if (c < NEXT_) { sq[f] = 0;         bq[f] = cb[c - NTOK]; }
    else                { sq[f] = -1;        bq[f] = 0.f; }
  }
  int sfirst = seg_of(colBase);
  int clast  = colBase + BN - 1; if (clast > NEXT_-1) clast = NEXT_-1;
  int slast  = seg_of(clast);
  int smin = sfirst, smax = slast;
  if (slast < sfirst){ smin = 0; smax = 4; }   // wrap tile at N_TOKEN boundary

#pragma unroll
  for (int i=0;i<4;++i){
#pragma unroll
    for (int r=0;r<4;++r){
      float e[4];
#pragma unroll
      for (int f=0;f<4;++f) e[f] = __expf(acc[i][f][r] + bq[f]);
      int rowg = rowBase + wm*64 + i*16 + (lane>>4)*4 + r;   // C/D: row=(l>>4)*4+reg
      for (int s2 = smin; s2 <= smax; ++s2){
        float p = 0.f;
#pragma unroll
        for (int f=0;f<4;++f) p += (sq[f]==s2) ? e[f] : 0.f;
#pragma unroll
        for (int off=1; off<16; off<<=1) p += __shfl_xor(p, off, 16);
        if ((lane & 15) == 0 && p != 0.f) atomicAdd(&accg[rowg*8 + s2], p);
      }
    }
  }
}

// One wave per row: target logit + routing logit + final nll.
__global__ __launch_bounds__(256) void finalize_kernel(
    const float* __restrict__ hidden, const int* __restrict__ target,
    const float* __restrict__ W,      const float* __restrict__ bias,
    const float* __restrict__ cw,     const float* __restrict__ cb,
    const float* __restrict__ accg,   float* __restrict__ out)
{
  const int row  = blockIdx.x * 4 + (threadIdx.x >> 6);
  const int lane = threadIdx.x & 63;
  const int t = target[row];

  const float4* h4 = reinterpret_cast<const float4*>(hidden + (size_t)row * D_DIM);
  const float4* w1 = reinterpret_cast<const float4*>(W + (size_t)t * D_DIM);
  int s = 0; const float* jraw = W; float jb = 0.f;
  if (t >= HEADN){
    if      (t < 20008)  { s=1; jraw = W;          jb = bias[0]; }  // j = 0
    else if (t < 20016)  { s=2; jraw = W + D_DIM;  jb = bias[1]; }  // j = 1
    else if (t < 200000) { s=3; jraw = cw + D_DIM; jb = cb[1];   }  // j = 20001 -> cluster 1
    else                 { s=4; jraw = cw;         jb = cb[0];   }  // j = 20000 -> cluster 0
  }
  const float4* w2 = reinterpret_cast<const float4*>(jraw);

  float p1 = 0.f, p2 = 0.f;
#pragma unroll
  for (int j=0;j<4;++j){
    float4 hv = h4[lane + 64*j];
    float4 av = w1[lane + 64*j];
    float4 bv = w2[lane + 64*j];
    p1 += hv.x*av.x + hv.y*av.y + hv.z*av.z + hv.w*av.w;
    p2 += hv.x*bv.x + hv.y*bv.y + hv.z*bv.z + hv.w*bv.w;
  }
#pragma unroll
  for (int off=32; off; off>>=1){
    p1 += __shfl_xor(p1, off, 64);
    p2 += __shfl_xor(p2, off, 64);
  }

  if (lane == 0){
    float lseH = __logf(accg[row*8 + 0]);
    float nll;
    if (t < HEADN){
      nll = -(p1 + bias[t] - lseH);
    } else {
      float lseS = __logf(accg[row*8 + s]);
      nll = -((p2 + jb - lseH) + (p1 + bias[t] - lseS));
    }
    out[row] = nll;
  }
}

extern "C" void kernel_launch(void* const* d_in, const int* in_sizes, int n_in,
                              void* d_out, int out_size, void* d_ws, size_t ws_size,
                              hipStream_t stream)
{
  const float* hidden = (const float*)d_in[0];
  const int*   target = (const int*)  d_in[1];
  const float* W      = (const float*)d_in[2];
  const float* bias   = (const float*)d_in[3];
  const float* cw     = (const float*)d_in[4];
  const float* cb     = (const float*)d_in[5];
  float* out  = (float*)d_out;
  float* accg = (float*)d_ws;          // [1024][8] fp32 sum-of-exp accumulators
  unsigned short* Ap = (unsigned short*)((char*)d_ws + APRIME_OFF);

  hipMemsetAsync(accg, 0, 1024*8*sizeof(float), stream);

  prep_convert<<<512, 256, 0, stream>>>(hidden, Ap);
  gemm_lse_adir<<<NBLK, NTHREADS, 0, stream>>>(Ap, W, bias, cw, cb, accg);
  finalize_kernel<<<256, 256, 0, stream>>>(hidden, target, W, bias, cw, cb, accg, out);
}